// Round 1
// baseline (177.451 us; speedup 1.0000x reference)
//
#include <hip/hip_runtime.h>

#define HW 103680           // 240*432
#define WORDS 1620          // HW/64
#define NP 256
#define NO 24
#define ND 256
#define EPSF 1e-8f
#define OUTM (NO*HW)        // 2488320

__device__ __forceinline__ float waveSum(float v) {
#pragma unroll
  for (int m = 1; m < 64; m <<= 1) v += __shfl_xor(v, m, 64);
  return v;
}
__device__ __forceinline__ float waveMax(float v) {
#pragma unroll
  for (int m = 1; m < 64; m <<= 1) v = fmaxf(v, __shfl_xor(v, m, 64));
  return v;
}

// --- inverse norms for proposed_feature (256 rows) and template_feature (48 rows) ---
__global__ __launch_bounds__(64) void norm_kernel(const float* __restrict__ pf,
                                                  const float* __restrict__ tf,
                                                  float* __restrict__ ink,
                                                  float* __restrict__ inq) {
  int r = blockIdx.x, lane = threadIdx.x;
  const float* src = (r < NP) ? (pf + r * ND) : (tf + (r - NP) * ND);
  float4 v = *(const float4*)(src + lane * 4);
  float ss = v.x * v.x + v.y * v.y + v.z * v.z + v.w * v.w;
  ss = waveSum(ss);
  if (lane == 0) {
    float inv = 1.0f / (sqrtf(ss) + EPSF);
    if (r < NP) ink[r] = inv; else inq[r - NP] = inv;
  }
}

// --- feature_sim[o][p] = (dot_t0*inq0 + dot_t1*inq1) * ink[p] / T,  one wave per (o,p) ---
__global__ __launch_bounds__(256) void featsim_kernel(const float* __restrict__ pf,
                                                      const float* __restrict__ tf,
                                                      const float* __restrict__ ink,
                                                      const float* __restrict__ inq,
                                                      float* __restrict__ fsim) {
  int wid = (blockIdx.x * 256 + threadIdx.x) >> 6;   // 0..6143
  int lane = threadIdx.x & 63;
  int o = wid >> 8, p = wid & 255;
  float4 f  = *(const float4*)(pf + p * ND + lane * 4);
  float4 a  = *(const float4*)(tf + o * ND + lane * 4);          // t=0
  float4 b  = *(const float4*)(tf + (NO + o) * ND + lane * 4);   // t=1
  float d0 = a.x * f.x + a.y * f.y + a.z * f.z + a.w * f.w;
  float d1 = b.x * f.x + b.y * f.y + b.z * f.z + b.w * f.w;
  float part = d0 * inq[o] + d1 * inq[NO + o];
  part = waveSum(part);
  if (lane == 0) fsim[wid] = part * ink[p] * 0.5f;   // /T (T=2)
}

// --- bit-pack a binary mask matrix [rows][HW] into u64 words + per-row counts ---
__global__ __launch_bounds__(256) void pack_kernel(const float* __restrict__ src,
                                                   unsigned long long* __restrict__ bits,
                                                   float* __restrict__ sums) {
  int row = blockIdx.y;
  int tid = threadIdx.x, lane = tid & 63, w = tid >> 6;
  const float* rp = src + (size_t)row * HW;
  int cnt = 0;
#pragma unroll 1
  for (int c = 0; c < 27; ++c) {
    int chunk = blockIdx.x * 27 + c;                 // 0..404
    float v = rp[chunk * 256 + tid];
    unsigned long long m = __ballot(v != 0.0f);
    cnt += (v != 0.0f) ? 1 : 0;
    if (lane == 0) bits[(size_t)row * WORDS + chunk * 4 + w] = m;
  }
  float f = waveSum((float)cnt);
  __shared__ float red[4];
  if (lane == 0) red[w] = f;
  __syncthreads();
  if (tid == 0) atomicAdd(sums + row, (red[0] + red[1]) + (red[2] + red[3]));
}

// --- inter[o][p] = popcount(Arow & Brow), one wave per (o,p) ---
__global__ __launch_bounds__(256) void inter_kernel(const unsigned long long* __restrict__ ab,
                                                    const unsigned long long* __restrict__ bb,
                                                    float* __restrict__ inter) {
  int wid = (blockIdx.x * 256 + threadIdx.x) >> 6;   // 0..6143
  int lane = threadIdx.x & 63;
  int o = wid >> 8, p = wid & 255;
  const unsigned long long* ar = ab + (size_t)o * WORDS;
  const unsigned long long* br = bb + (size_t)p * WORDS;
  int cnt = 0;
  for (int w = lane; w < WORDS; w += 64)
    cnt += (int)__popcll(ar[w] & br[w]);
  float f = waveSum((float)cnt);
  if (lane == 0) inter[wid] = f;
}

// --- iou + sim + 20x5 projected-gradient relaxation + scores.  1 wave per row o. ---
__global__ __launch_bounds__(64) void solve_kernel(const float* __restrict__ inter,
                                                   const float* __restrict__ bsum,
                                                   const float* __restrict__ asum,
                                                   const float* __restrict__ fsim,
                                                   const float* __restrict__ score,
                                                   float* __restrict__ binX,
                                                   float* __restrict__ out) {
  int o = blockIdx.x, lane = threadIdx.x;
  float4 iv4 = *(const float4*)(inter + o * NP + lane * 4);
  float4 fs4 = *(const float4*)(fsim + o * NP + lane * 4);
  float4 bs4 = *(const float4*)(bsum + lane * 4);
  float as = asum[o];
  float ivv[4] = {iv4.x, iv4.y, iv4.z, iv4.w};
  float fsv[4] = {fs4.x, fs4.y, fs4.z, fs4.w};
  float bsv[4] = {bs4.x, bs4.y, bs4.z, bs4.w};
  float sim[4], C[4], X[4], Xs[4];
#pragma unroll
  for (int j = 0; j < 4; ++j) {
    float uni = as + bsv[j] - ivv[j];
    float iou = ivv[j] / (uni + EPSF);
    sim[j] = fsv[j] * 0.5f + iou * 0.5f;
    C[j] = -sim[j];
    X[j] = 1.0f / 256.0f;
    Xs[j] = 0.0f;
  }
  for (int it = 0; it < 20; ++it) {
#pragma unroll
    for (int j = 0; j < 4; ++j) X[j] = X[j] - 0.1f * C[j];
    for (int k = 0; k < 5; ++k) {
#pragma unroll
      for (int j = 0; j < 4; ++j) X[j] = fminf(fmaxf(X[j], 0.0f), 1.0f);
      float s = (X[0] + X[1]) + (X[2] + X[3]);
      s = waveSum(s);
#pragma unroll
      for (int j = 0; j < 4; ++j) X[j] = X[j] / (s + EPSF);
    }
#pragma unroll
    for (int j = 0; j < 4; ++j) Xs[j] += X[j];
  }
  float R[4], bx[4];
#pragma unroll
  for (int j = 0; j < 4; ++j) {
    R[j] = Xs[j] / 20.0f;
    bx[j] = (R[j] > 0.01f) ? R[j] : 0.0f;
  }
  *(float4*)(binX + o * NP + lane * 4) = make_float4(bx[0], bx[1], bx[2], bx[3]);
  float mv = -1e30f;
#pragma unroll
  for (int j = 0; j < 4; ++j)
    mv = fmaxf(mv, fminf(fmaxf(R[j], 0.0f), 1.0f) * sim[j]);
  mv = waveMax(mv);
  float4 sc4 = *(const float4*)(score + lane * 4);
  float dv = ((sc4.x * bx[0]) + (sc4.y * bx[1])) + ((sc4.z * bx[2]) + (sc4.w * bx[3]));
  dv = waveSum(dv);
  if (lane == 0) { out[OUTM + o] = mv; out[OUTM + NO + o] = dv; }
}

// --- full_outmask[o][hw] = sum_p binX[o][p] * bit(p,hw).  One wave per 64-hw word. ---
__global__ __launch_bounds__(256) void outmask_kernel(const unsigned long long* __restrict__ bb,
                                                      const float* __restrict__ binX,
                                                      float* __restrict__ out) {
  int word = __builtin_amdgcn_readfirstlane((int)(blockIdx.x * 4 + (threadIdx.x >> 6)));
  int lane = threadIdx.x & 63;
  float acc[NO];
#pragma unroll
  for (int o = 0; o < NO; ++o) acc[o] = 0.0f;
  for (int p = 0; p < NP; ++p) {
    unsigned long long m = bb[(size_t)p * WORDS + word];
    float bit = (float)((m >> lane) & 1ull);
#pragma unroll
    for (int o = 0; o < NO; ++o)
      acc[o] = fmaf(binX[o * NP + p], bit, acc[o]);
  }
  int hw = word * 64 + lane;
#pragma unroll
  for (int o = 0; o < NO; ++o) out[o * HW + hw] = acc[o];
}

extern "C" void kernel_launch(void* const* d_in, const int* in_sizes, int n_in,
                              void* d_out, int out_size, void* d_ws, size_t ws_size,
                              hipStream_t stream) {
  const float* pf = (const float*)d_in[0];   // proposed_feature [256][256]
  const float* pm = (const float*)d_in[1];   // proposed_mask    [256][240][432]
  const float* tf = (const float*)d_in[2];   // template_feature [2][24][256]
  const float* ml = (const float*)d_in[3];   // mask_last_occ.   [24][240][432]
  const float* sc = (const float*)d_in[4];   // proposal_score   [256]
  float* out = (float*)d_out;
  char* ws = (char*)d_ws;

  // ws layout (bytes):
  unsigned long long* bbits = (unsigned long long*)(ws);             // 256*1620*8 = 3,317,760
  unsigned long long* abits = (unsigned long long*)(ws + 3317760);   // 24*1620*8  =   311,040
  float* bsum  = (float*)(ws + 3628800);   // 256
  float* asum  = (float*)(ws + 3629824);   // 24
  float* ink   = (float*)(ws + 3629920);   // 256
  float* inq   = (float*)(ws + 3630944);   // 48
  float* fsim  = (float*)(ws + 3631136);   // 24*256
  float* interm= (float*)(ws + 3655712);   // 24*256
  float* binX  = (float*)(ws + 3680288);   // 24*256

  // zero the atomic accumulators (bsum+asum, contiguous 1024+96 bytes)
  hipMemsetAsync(ws + 3628800, 0, 1120, stream);

  hipLaunchKernelGGL(norm_kernel,    dim3(304),     dim3(64),  0, stream, pf, tf, ink, inq);
  hipLaunchKernelGGL(featsim_kernel, dim3(1536),    dim3(256), 0, stream, pf, tf, ink, inq, fsim);
  hipLaunchKernelGGL(pack_kernel,    dim3(15, 256), dim3(256), 0, stream, pm, bbits, bsum);
  hipLaunchKernelGGL(pack_kernel,    dim3(15, 24),  dim3(256), 0, stream, ml, abits, asum);
  hipLaunchKernelGGL(inter_kernel,   dim3(1536),    dim3(256), 0, stream, abits, bbits, interm);
  hipLaunchKernelGGL(solve_kernel,   dim3(24),      dim3(64),  0, stream, interm, bsum, asum, fsim, sc, binX, out);
  hipLaunchKernelGGL(outmask_kernel, dim3(405),     dim3(256), 0, stream, bbits, binX, out);
}

// Round 2
// 100.941 us; speedup vs baseline: 1.7580x; 1.7580x over previous
//
#include <hip/hip_runtime.h>

#define HW 103680           // 240*432
#define WORDS 1620          // HW/64
#define NP 256
#define NO 24
#define ND 256
#define EPSF 1e-8f
#define OUTM (NO*HW)        // 2488320

__device__ __forceinline__ float waveSum(float v) {
#pragma unroll
  for (int m = 1; m < 64; m <<= 1) v += __shfl_xor(v, m, 64);
  return v;
}
__device__ __forceinline__ float waveMax(float v) {
#pragma unroll
  for (int m = 1; m < 64; m <<= 1) v = fmaxf(v, __shfl_xor(v, m, 64));
  return v;
}

// --- feature_sim[o][p] with norms fused. One wave per (o,p). ---
__global__ __launch_bounds__(256) void featsim_kernel(const float* __restrict__ pf,
                                                      const float* __restrict__ tf,
                                                      float* __restrict__ fsim) {
  int wid = (blockIdx.x * 256 + threadIdx.x) >> 6;   // 0..6143
  int lane = threadIdx.x & 63;
  int o = wid >> 8, p = wid & 255;
  float4 f  = *(const float4*)(pf + p * ND + lane * 4);
  float4 a  = *(const float4*)(tf + o * ND + lane * 4);          // t=0
  float4 b  = *(const float4*)(tf + (NO + o) * ND + lane * 4);   // t=1
  float nf = f.x*f.x + f.y*f.y + f.z*f.z + f.w*f.w;
  float na = a.x*a.x + a.y*a.y + a.z*a.z + a.w*a.w;
  float nb = b.x*b.x + b.y*b.y + b.z*b.z + b.w*b.w;
  float d0 = a.x*f.x + a.y*f.y + a.z*f.z + a.w*f.w;
  float d1 = b.x*f.x + b.y*f.y + b.z*f.z + b.w*f.w;
  nf = waveSum(nf); na = waveSum(na); nb = waveSum(nb);
  d0 = waveSum(d0); d1 = waveSum(d1);
  if (lane == 0) {
    float invf = 1.0f / (sqrtf(nf) + EPSF);
    float inva = 1.0f / (sqrtf(na) + EPSF);
    float invb = 1.0f / (sqrtf(nb) + EPSF);
    fsim[wid] = (d0 * inva + d1 * invb) * invf * 0.5f;   // /T (T=2)
  }
}

// --- bit-pack a binary mask matrix [rows][HW] into u64 words + per-row counts ---
__global__ __launch_bounds__(256) void pack_kernel(const float* __restrict__ src,
                                                   unsigned long long* __restrict__ bits,
                                                   float* __restrict__ sums) {
  int row = blockIdx.y;
  int tid = threadIdx.x, lane = tid & 63, w = tid >> 6;
  const float* rp = src + (size_t)row * HW;
  int cnt = 0;
#pragma unroll 1
  for (int c = 0; c < 27; ++c) {
    int chunk = blockIdx.x * 27 + c;                 // 0..404
    float v = rp[chunk * 256 + tid];
    unsigned long long m = __ballot(v != 0.0f);
    cnt += (v != 0.0f) ? 1 : 0;
    if (lane == 0) bits[(size_t)row * WORDS + chunk * 4 + w] = m;
  }
  float f = waveSum((float)cnt);
  __shared__ float red[4];
  if (lane == 0) red[w] = f;
  __syncthreads();
  if (tid == 0) atomicAdd(sums + row, (red[0] + red[1]) + (red[2] + red[3]));
}

// --- inter[o][p] = popcount(Arow & Brow), one wave per (o,p) ---
__global__ __launch_bounds__(256) void inter_kernel(const unsigned long long* __restrict__ ab,
                                                    const unsigned long long* __restrict__ bb,
                                                    float* __restrict__ inter) {
  int wid = (blockIdx.x * 256 + threadIdx.x) >> 6;   // 0..6143
  int lane = threadIdx.x & 63;
  int o = wid >> 8, p = wid & 255;
  const unsigned long long* ar = ab + (size_t)o * WORDS;
  const unsigned long long* br = bb + (size_t)p * WORDS;
  int cnt = 0;
  for (int w = lane; w < WORDS; w += 64)
    cnt += (int)__popcll(ar[w] & br[w]);
  float f = waveSum((float)cnt);
  if (lane == 0) inter[wid] = f;
}

// --- iou + sim + 20x5 relaxation + scores + nonzero compaction. 1 wave per o. ---
__global__ __launch_bounds__(64) void solve_kernel(const float* __restrict__ inter,
                                                   const float* __restrict__ bsum,
                                                   const float* __restrict__ asum,
                                                   const float* __restrict__ fsim,
                                                   const float* __restrict__ score,
                                                   int* __restrict__ nzidx,
                                                   float* __restrict__ nzval,
                                                   int* __restrict__ nzcnt,
                                                   float* __restrict__ out) {
  int o = blockIdx.x, lane = threadIdx.x;
  float4 iv4 = *(const float4*)(inter + o * NP + lane * 4);
  float4 fs4 = *(const float4*)(fsim + o * NP + lane * 4);
  float4 bs4 = *(const float4*)(bsum + lane * 4);
  float as = asum[o];
  float ivv[4] = {iv4.x, iv4.y, iv4.z, iv4.w};
  float fsv[4] = {fs4.x, fs4.y, fs4.z, fs4.w};
  float bsv[4] = {bs4.x, bs4.y, bs4.z, bs4.w};
  float sim[4], C[4], X[4], Xs[4];
#pragma unroll
  for (int j = 0; j < 4; ++j) {
    float uni = as + bsv[j] - ivv[j];
    float iou = ivv[j] / (uni + EPSF);
    sim[j] = fsv[j] * 0.5f + iou * 0.5f;
    C[j] = -sim[j];
    X[j] = 1.0f / 256.0f;
    Xs[j] = 0.0f;
  }
  for (int it = 0; it < 20; ++it) {
#pragma unroll
    for (int j = 0; j < 4; ++j) X[j] = X[j] - 0.1f * C[j];
    for (int k = 0; k < 5; ++k) {
#pragma unroll
      for (int j = 0; j < 4; ++j) X[j] = fminf(fmaxf(X[j], 0.0f), 1.0f);
      float s = (X[0] + X[1]) + (X[2] + X[3]);
      s = waveSum(s);
#pragma unroll
      for (int j = 0; j < 4; ++j) X[j] = X[j] / (s + EPSF);
    }
#pragma unroll
    for (int j = 0; j < 4; ++j) Xs[j] += X[j];
  }
  float R[4], bx[4];
#pragma unroll
  for (int j = 0; j < 4; ++j) {
    R[j] = Xs[j] / 20.0f;
    bx[j] = (R[j] > 0.01f) ? R[j] : 0.0f;
  }
  // compact nonzeros of this row into (p, val) lists
  unsigned long long lt = (1ull << lane) - 1ull;
  int base = 0;
#pragma unroll
  for (int j = 0; j < 4; ++j) {
    unsigned long long m = __ballot(bx[j] != 0.0f);
    if (bx[j] != 0.0f) {
      int pos = base + (int)__popcll(m & lt);
      nzidx[o * NP + pos] = lane * 4 + j;
      nzval[o * NP + pos] = bx[j];
    }
    base += (int)__popcll(m);
  }
  if (lane == 0) nzcnt[o] = base;
  // scores
  float mv = -1e30f;
#pragma unroll
  for (int j = 0; j < 4; ++j)
    mv = fmaxf(mv, fminf(fmaxf(R[j], 0.0f), 1.0f) * sim[j]);
  mv = waveMax(mv);
  float4 sc4 = *(const float4*)(score + lane * 4);
  float dv = ((sc4.x * bx[0]) + (sc4.y * bx[1])) + ((sc4.z * bx[2]) + (sc4.w * bx[3]));
  dv = waveSum(dv);
  if (lane == 0) { out[OUTM + o] = mv; out[OUTM + NO + o] = dv; }
}

// --- full_outmask[o][hw] = sum over active p of val * pm[p][hw], float4 per thread ---
__global__ __launch_bounds__(256) void outmask_kernel(const float* __restrict__ pm,
                                                      const int* __restrict__ nzidx,
                                                      const float* __restrict__ nzval,
                                                      const int* __restrict__ nzcnt,
                                                      float* __restrict__ out) {
  int o = blockIdx.y;
  int t = blockIdx.x * 256 + threadIdx.x;   // float4 index
  int hw4 = t * 4;
  if (hw4 >= HW) return;
  int cnt = nzcnt[o];
  float4 acc = make_float4(0.0f, 0.0f, 0.0f, 0.0f);
  for (int i = 0; i < cnt; ++i) {
    int p = nzidx[o * NP + i];
    float v = nzval[o * NP + i];
    float4 m = *(const float4*)(pm + (size_t)p * HW + hw4);
    acc.x = fmaf(v, m.x, acc.x);
    acc.y = fmaf(v, m.y, acc.y);
    acc.z = fmaf(v, m.z, acc.z);
    acc.w = fmaf(v, m.w, acc.w);
  }
  *(float4*)(out + (size_t)o * HW + hw4) = acc;
}

extern "C" void kernel_launch(void* const* d_in, const int* in_sizes, int n_in,
                              void* d_out, int out_size, void* d_ws, size_t ws_size,
                              hipStream_t stream) {
  const float* pf = (const float*)d_in[0];   // proposed_feature [256][256]
  const float* pm = (const float*)d_in[1];   // proposed_mask    [256][240][432]
  const float* tf = (const float*)d_in[2];   // template_feature [2][24][256]
  const float* ml = (const float*)d_in[3];   // mask_last_occ.   [24][240][432]
  const float* sc = (const float*)d_in[4];   // proposal_score   [256]
  float* out = (float*)d_out;
  char* ws = (char*)d_ws;

  // ws layout (bytes):
  unsigned long long* bbits = (unsigned long long*)(ws);             // 256*1620*8 = 3,317,760
  unsigned long long* abits = (unsigned long long*)(ws + 3317760);   // 24*1620*8  =   311,040
  // nz lists overlay the abits region (dead after inter_kernel):
  int*   nzidx = (int*)(ws + 3317760);            // 24*256*4 = 24,576
  float* nzval = (float*)(ws + 3317760 + 24576);  // 24,576
  int*   nzcnt = (int*)(ws + 3317760 + 49152);    // 96
  float* bsum  = (float*)(ws + 3628800);   // 256
  float* asum  = (float*)(ws + 3629824);   // 24
  float* fsim  = (float*)(ws + 3631136);   // 24*256
  float* interm= (float*)(ws + 3655712);   // 24*256

  // zero the atomic accumulators (bsum+asum, contiguous)
  hipMemsetAsync(ws + 3628800, 0, 1120, stream);

  hipLaunchKernelGGL(featsim_kernel, dim3(1536),    dim3(256), 0, stream, pf, tf, fsim);
  hipLaunchKernelGGL(pack_kernel,    dim3(15, 256), dim3(256), 0, stream, pm, bbits, bsum);
  hipLaunchKernelGGL(pack_kernel,    dim3(15, 24),  dim3(256), 0, stream, ml, abits, asum);
  hipLaunchKernelGGL(inter_kernel,   dim3(1536),    dim3(256), 0, stream, abits, bbits, interm);
  hipLaunchKernelGGL(solve_kernel,   dim3(24),      dim3(64),  0, stream, interm, bsum, asum, fsim, sc,
                     nzidx, nzval, nzcnt, out);
  hipLaunchKernelGGL(outmask_kernel, dim3(102, 24), dim3(256), 0, stream, pm, nzidx, nzval, nzcnt, out);
}

// Round 3
// 85.153 us; speedup vs baseline: 2.0839x; 1.1854x over previous
//
#include <hip/hip_runtime.h>

#define HW 103680           // 240*432
#define WORDS 1620          // HW/64
#define NP 256
#define NO 24
#define ND 256
#define EPSF 1e-8f
#define OUTM (NO*HW)        // 2488320

__device__ __forceinline__ float waveSum(float v) {
#pragma unroll
  for (int m = 1; m < 64; m <<= 1) v += __shfl_xor(v, m, 64);
  return v;
}
__device__ __forceinline__ float waveMax(float v) {
#pragma unroll
  for (int m = 1; m < 64; m <<= 1) v = fmaxf(v, __shfl_xor(v, m, 64));
  return v;
}

// --- feature_sim[o][p] with norms fused. One wave per (o,p). ---
__global__ __launch_bounds__(256) void featsim_kernel(const float* __restrict__ pf,
                                                      const float* __restrict__ tf,
                                                      float* __restrict__ fsim) {
  int wid = (blockIdx.x * 256 + threadIdx.x) >> 6;   // 0..6143
  int lane = threadIdx.x & 63;
  int o = wid >> 8, p = wid & 255;
  float4 f  = *(const float4*)(pf + p * ND + lane * 4);
  float4 a  = *(const float4*)(tf + o * ND + lane * 4);          // t=0
  float4 b  = *(const float4*)(tf + (NO + o) * ND + lane * 4);   // t=1
  float nf = f.x*f.x + f.y*f.y + f.z*f.z + f.w*f.w;
  float na = a.x*a.x + a.y*a.y + a.z*a.z + a.w*a.w;
  float nb = b.x*b.x + b.y*b.y + b.z*b.z + b.w*b.w;
  float d0 = a.x*f.x + a.y*f.y + a.z*f.z + a.w*f.w;
  float d1 = b.x*f.x + b.y*f.y + b.z*f.z + b.w*f.w;
  nf = waveSum(nf); na = waveSum(na); nb = waveSum(nb);
  d0 = waveSum(d0); d1 = waveSum(d1);
  if (lane == 0) {
    float invf = 1.0f / (sqrtf(nf) + EPSF);
    float inva = 1.0f / (sqrtf(na) + EPSF);
    float invb = 1.0f / (sqrtf(nb) + EPSF);
    fsim[wid] = (d0 * inva + d1 * invb) * invf * 0.5f;   // /T (T=2)
  }
}

// --- bit-pack BOTH mask matrices; partial sums per (row, block) — no atomics, no init ---
// rows 0..255 -> pm/bbits, rows 256..279 -> ml/abits
__global__ __launch_bounds__(256) void pack_kernel(const float* __restrict__ pm,
                                                   const float* __restrict__ ml,
                                                   unsigned long long* __restrict__ bbits,
                                                   unsigned long long* __restrict__ abits,
                                                   float* __restrict__ psum) {
  int row = blockIdx.y;
  int tid = threadIdx.x, lane = tid & 63, w = tid >> 6;
  const float* rp;
  unsigned long long* bits;
  if (row < NP) { rp = pm + (size_t)row * HW;        bits = bbits + (size_t)row * WORDS; }
  else          { rp = ml + (size_t)(row - NP) * HW; bits = abits + (size_t)(row - NP) * WORDS; }
  int cnt = 0;
#pragma unroll 1
  for (int c = 0; c < 27; ++c) {
    int chunk = blockIdx.x * 27 + c;                 // 0..404
    float v = rp[chunk * 256 + tid];
    unsigned long long m = __ballot(v != 0.0f);
    cnt += (v != 0.0f) ? 1 : 0;
    if (lane == 0) bits[chunk * 4 + w] = m;
  }
  float f = waveSum((float)cnt);
  __shared__ float red[4];
  if (lane == 0) red[w] = f;
  __syncthreads();
  if (tid == 0) psum[row * 16 + blockIdx.x] = (red[0] + red[1]) + (red[2] + red[3]);
}

// --- inter[o][p] = popcount(Arow & Brow), one wave per (o,p) ---
__global__ __launch_bounds__(256) void inter_kernel(const unsigned long long* __restrict__ ab,
                                                    const unsigned long long* __restrict__ bb,
                                                    float* __restrict__ inter) {
  int wid = (blockIdx.x * 256 + threadIdx.x) >> 6;   // 0..6143
  int lane = threadIdx.x & 63;
  int o = wid >> 8, p = wid & 255;
  const unsigned long long* ar = ab + (size_t)o * WORDS;
  const unsigned long long* br = bb + (size_t)p * WORDS;
  int cnt = 0;
  for (int w = lane; w < WORDS; w += 64)
    cnt += (int)__popcll(ar[w] & br[w]);
  float f = waveSum((float)cnt);
  if (lane == 0) inter[wid] = f;
}

// --- iou + sim + 20x5 relaxation + scores + nonzero compaction. 1 wave per o. ---
__global__ __launch_bounds__(64) void solve_kernel(const float* __restrict__ inter,
                                                   const float* __restrict__ psum,
                                                   const float* __restrict__ fsim,
                                                   const float* __restrict__ score,
                                                   int* __restrict__ nzidx,
                                                   float* __restrict__ nzval,
                                                   int* __restrict__ nzcnt,
                                                   float* __restrict__ out) {
  int o = blockIdx.x, lane = threadIdx.x;
  float4 iv4 = *(const float4*)(inter + o * NP + lane * 4);
  float4 fs4 = *(const float4*)(fsim + o * NP + lane * 4);
  float ivv[4] = {iv4.x, iv4.y, iv4.z, iv4.w};
  float fsv[4] = {fs4.x, fs4.y, fs4.z, fs4.w};
  // reduce partial row-sums: bsum for my 4 proposals, asum for row o
  float bsv[4];
#pragma unroll
  for (int j = 0; j < 4; ++j) {
    float s = 0.0f;
    const float* pp = psum + (lane * 4 + j) * 16;
    for (int b = 0; b < 15; ++b) s += pp[b];
    bsv[j] = s;
  }
  float as = 0.0f;
  {
    const float* pp = psum + (NP + o) * 16;
    for (int b = 0; b < 15; ++b) as += pp[b];
  }
  float sim[4], C[4], X[4], Xs[4];
#pragma unroll
  for (int j = 0; j < 4; ++j) {
    float uni = as + bsv[j] - ivv[j];
    float iou = ivv[j] / (uni + EPSF);
    sim[j] = fsv[j] * 0.5f + iou * 0.5f;
    C[j] = -sim[j];
    X[j] = 1.0f / 256.0f;
    Xs[j] = 0.0f;
  }
  for (int it = 0; it < 20; ++it) {
#pragma unroll
    for (int j = 0; j < 4; ++j) X[j] = X[j] - 0.1f * C[j];
    for (int k = 0; k < 5; ++k) {
#pragma unroll
      for (int j = 0; j < 4; ++j) X[j] = fminf(fmaxf(X[j], 0.0f), 1.0f);
      float s = (X[0] + X[1]) + (X[2] + X[3]);
      s = waveSum(s);
#pragma unroll
      for (int j = 0; j < 4; ++j) X[j] = X[j] / (s + EPSF);
    }
#pragma unroll
    for (int j = 0; j < 4; ++j) Xs[j] += X[j];
  }
  float R[4], bx[4];
#pragma unroll
  for (int j = 0; j < 4; ++j) {
    R[j] = Xs[j] / 20.0f;
    bx[j] = (R[j] > 0.01f) ? R[j] : 0.0f;
  }
  // compact nonzeros of this row into (p, val) lists
  unsigned long long lt = (1ull << lane) - 1ull;
  int base = 0;
#pragma unroll
  for (int j = 0; j < 4; ++j) {
    unsigned long long m = __ballot(bx[j] != 0.0f);
    if (bx[j] != 0.0f) {
      int pos = base + (int)__popcll(m & lt);
      nzidx[o * NP + pos] = lane * 4 + j;
      nzval[o * NP + pos] = bx[j];
    }
    base += (int)__popcll(m);
  }
  if (lane == 0) nzcnt[o] = base;
  // scores
  float mv = -1e30f;
#pragma unroll
  for (int j = 0; j < 4; ++j)
    mv = fmaxf(mv, fminf(fmaxf(R[j], 0.0f), 1.0f) * sim[j]);
  mv = waveMax(mv);
  float4 sc4 = *(const float4*)(score + lane * 4);
  float dv = ((sc4.x * bx[0]) + (sc4.y * bx[1])) + ((sc4.z * bx[2]) + (sc4.w * bx[3]));
  dv = waveSum(dv);
  if (lane == 0) { out[OUTM + o] = mv; out[OUTM + NO + o] = dv; }
}

// --- full_outmask[o][hw] = sum over active p of val * pm[p][hw], float4 per thread ---
__global__ __launch_bounds__(256) void outmask_kernel(const float* __restrict__ pm,
                                                      const int* __restrict__ nzidx,
                                                      const float* __restrict__ nzval,
                                                      const int* __restrict__ nzcnt,
                                                      float* __restrict__ out) {
  int o = blockIdx.y;
  int t = blockIdx.x * 256 + threadIdx.x;   // float4 index
  int hw4 = t * 4;
  if (hw4 >= HW) return;
  int cnt = nzcnt[o];
  float4 acc = make_float4(0.0f, 0.0f, 0.0f, 0.0f);
  for (int i = 0; i < cnt; ++i) {
    int p = nzidx[o * NP + i];
    float v = nzval[o * NP + i];
    float4 m = *(const float4*)(pm + (size_t)p * HW + hw4);
    acc.x = fmaf(v, m.x, acc.x);
    acc.y = fmaf(v, m.y, acc.y);
    acc.z = fmaf(v, m.z, acc.z);
    acc.w = fmaf(v, m.w, acc.w);
  }
  *(float4*)(out + (size_t)o * HW + hw4) = acc;
}

extern "C" void kernel_launch(void* const* d_in, const int* in_sizes, int n_in,
                              void* d_out, int out_size, void* d_ws, size_t ws_size,
                              hipStream_t stream) {
  const float* pf = (const float*)d_in[0];   // proposed_feature [256][256]
  const float* pm = (const float*)d_in[1];   // proposed_mask    [256][240][432]
  const float* tf = (const float*)d_in[2];   // template_feature [2][24][256]
  const float* ml = (const float*)d_in[3];   // mask_last_occ.   [24][240][432]
  const float* sc = (const float*)d_in[4];   // proposal_score   [256]
  float* out = (float*)d_out;
  char* ws = (char*)d_ws;

  // ws layout (bytes):
  unsigned long long* bbits = (unsigned long long*)(ws);             // 256*1620*8 = 3,317,760
  unsigned long long* abits = (unsigned long long*)(ws + 3317760);   // 24*1620*8  =   311,040
  // nz lists overlay the abits region (dead after inter_kernel):
  int*   nzidx = (int*)(ws + 3317760);            // 24*256*4 = 24,576
  float* nzval = (float*)(ws + 3317760 + 24576);  // 24,576
  int*   nzcnt = (int*)(ws + 3317760 + 49152);    // 96
  float* fsim  = (float*)(ws + 3631136);   // 24*256
  float* interm= (float*)(ws + 3655712);   // 24*256
  float* psum  = (float*)(ws + 3680288);   // 280*16 = 17,920 B

  hipLaunchKernelGGL(pack_kernel,    dim3(15, 280), dim3(256), 0, stream, pm, ml, bbits, abits, psum);
  hipLaunchKernelGGL(featsim_kernel, dim3(1536),    dim3(256), 0, stream, pf, tf, fsim);
  hipLaunchKernelGGL(inter_kernel,   dim3(1536),    dim3(256), 0, stream, abits, bbits, interm);
  hipLaunchKernelGGL(solve_kernel,   dim3(24),      dim3(64),  0, stream, interm, psum, fsim, sc,
                     nzidx, nzval, nzcnt, out);
  hipLaunchKernelGGL(outmask_kernel, dim3(102, 24), dim3(256), 0, stream, pm, nzidx, nzval, nzcnt, out);
}

// Round 4
// 70.810 us; speedup vs baseline: 2.5060x; 1.2026x over previous
//
#include <hip/hip_runtime.h>

#define HW 103680           // 240*432
#define WORDS 1620          // HW/64 (= 405 groups * 4 ballot-words)
#define NGRP 405            // 256-pixel groups per row
#define NP 256
#define NO 24
#define ND 256
#define EPSF 1e-8f
#define OUTM (NO*HW)        // 2488320

typedef unsigned long long u64;

__device__ __forceinline__ float waveSum(float v) {
#pragma unroll
  for (int m = 1; m < 64; m <<= 1) v += __shfl_xor(v, m, 64);
  return v;
}
__device__ __forceinline__ float waveMax(float v) {
#pragma unroll
  for (int m = 1; m < 64; m <<= 1) v = fmaxf(v, __shfl_xor(v, m, 64));
  return v;
}

// --- bit-pack BOTH mask matrices with float4 loads + 4 ballots per load. ---
// Word order within a row is "group-major, component-minor" — consistent for
// both packs, so popcount(a & b) is unaffected. rows 0..255 -> pm, 256.. -> ml.
// 64 waves/row: wave gid does groups [gid*6, gid*6+6), waves 0..20 also do 384+gid.
__global__ __launch_bounds__(256) void pack_kernel(const float* __restrict__ pm,
                                                   const float* __restrict__ ml,
                                                   u64* __restrict__ bbits,
                                                   u64* __restrict__ abits,
                                                   float* __restrict__ psum) {
  int row = blockIdx.y;
  int tid = threadIdx.x, lane = tid & 63, w = tid >> 6;
  const float* rp;
  u64* bits;
  if (row < NP) { rp = pm + (size_t)row * HW;        bits = bbits + (size_t)row * WORDS; }
  else          { rp = ml + (size_t)(row - NP) * HW; bits = abits + (size_t)(row - NP) * WORDS; }
  int gid = blockIdx.x * 4 + w;        // 0..63
  const float* base = rp + (size_t)(gid * 6) * 256 + lane * 4;
  float4 v[6];
#pragma unroll
  for (int k = 0; k < 6; ++k) v[k] = *(const float4*)(base + k * 256);
  int cnt = 0;
#pragma unroll
  for (int k = 0; k < 6; ++k) {
    int g = gid * 6 + k;
    u64 m0 = __ballot(v[k].x != 0.0f);
    u64 m1 = __ballot(v[k].y != 0.0f);
    u64 m2 = __ballot(v[k].z != 0.0f);
    u64 m3 = __ballot(v[k].w != 0.0f);
    cnt += __popcll(m0) + __popcll(m1) + __popcll(m2) + __popcll(m3);
    if (lane == 0) {
      ulonglong2 s0; s0.x = m0; s0.y = m1;
      ulonglong2 s1; s1.x = m2; s1.y = m3;
      *(ulonglong2*)(bits + g * 4)     = s0;
      *(ulonglong2*)(bits + g * 4 + 2) = s1;
    }
  }
  if (gid < NGRP - 384) {              // remainder groups 384..404
    int g = 384 + gid;
    float4 vv = *(const float4*)(rp + (size_t)g * 256 + lane * 4);
    u64 m0 = __ballot(vv.x != 0.0f);
    u64 m1 = __ballot(vv.y != 0.0f);
    u64 m2 = __ballot(vv.z != 0.0f);
    u64 m3 = __ballot(vv.w != 0.0f);
    cnt += __popcll(m0) + __popcll(m1) + __popcll(m2) + __popcll(m3);
    if (lane == 0) {
      ulonglong2 s0; s0.x = m0; s0.y = m1;
      ulonglong2 s1; s1.x = m2; s1.y = m3;
      *(ulonglong2*)(bits + g * 4)     = s0;
      *(ulonglong2*)(bits + g * 4 + 2) = s1;
    }
  }
  __shared__ int red[4];
  if (lane == 0) red[w] = cnt;
  __syncthreads();
  if (tid == 0) psum[row * 16 + blockIdx.x] =
      (float)((red[0] + red[1]) + (red[2] + red[3]));
}

// --- fused cost matrix: C[o][p] = -(0.5*feature_sim + 0.5*iou). One wave/(o,p). ---
__global__ __launch_bounds__(256) void interfeat_kernel(const u64* __restrict__ ab,
                                                        const u64* __restrict__ bb,
                                                        const float* __restrict__ pf,
                                                        const float* __restrict__ tf,
                                                        const float* __restrict__ psum,
                                                        float* __restrict__ C) {
  int wid = (blockIdx.x * 256 + threadIdx.x) >> 6;   // 0..6143
  int lane = threadIdx.x & 63;
  int o = wid >> 8, p = wid & 255;
  // popcount intersection
  const u64* ar = ab + (size_t)o * WORDS;
  const u64* br = bb + (size_t)p * WORDS;
  int cnt = 0;
  for (int w = lane; w < WORDS; w += 64)
    cnt += (int)__popcll(ar[w] & br[w]);
  float inter = waveSum((float)cnt);
  // feature cosine (norms fused)
  float4 f = *(const float4*)(pf + p * ND + lane * 4);
  float4 a = *(const float4*)(tf + o * ND + lane * 4);          // t=0
  float4 b = *(const float4*)(tf + (NO + o) * ND + lane * 4);   // t=1
  float nf = f.x*f.x + f.y*f.y + f.z*f.z + f.w*f.w;
  float na = a.x*a.x + a.y*a.y + a.z*a.z + a.w*a.w;
  float nb = b.x*b.x + b.y*b.y + b.z*b.z + b.w*b.w;
  float d0 = a.x*f.x + a.y*f.y + a.z*f.z + a.w*f.w;
  float d1 = b.x*f.x + b.y*f.y + b.z*f.z + b.w*f.w;
  nf = waveSum(nf); na = waveSum(na); nb = waveSum(nb);
  d0 = waveSum(d0); d1 = waveSum(d1);
  if (lane == 0) {
    float bs = 0.0f, as = 0.0f;
    const float* pb = psum + p * 16;
    const float* pa = psum + (NP + o) * 16;
#pragma unroll
    for (int q = 0; q < 16; ++q) { bs += pb[q]; as += pa[q]; }
    float invf = 1.0f / (sqrtf(nf) + EPSF);
    float inva = 1.0f / (sqrtf(na) + EPSF);
    float invb = 1.0f / (sqrtf(nb) + EPSF);
    float fs  = (d0 * inva + d1 * invb) * invf * 0.5f;   // /T (T=2)
    float uni = as + bs - inter;
    float iou = inter / (uni + EPSF);
    C[wid] = -(fs * 0.5f + iou * 0.5f);
  }
}

// --- 20x5 relaxation + scores + nonzero compaction. 1 wave per row o. ---
__global__ __launch_bounds__(64) void solve_kernel(const float* __restrict__ Cm,
                                                   const float* __restrict__ score,
                                                   int* __restrict__ nzidx,
                                                   float* __restrict__ nzval,
                                                   int* __restrict__ nzcnt,
                                                   float* __restrict__ out) {
  int o = blockIdx.x, lane = threadIdx.x;
  float4 c4 = *(const float4*)(Cm + o * NP + lane * 4);
  float C[4] = {c4.x, c4.y, c4.z, c4.w};
  float sim[4], X[4], Xs[4];
#pragma unroll
  for (int j = 0; j < 4; ++j) {
    sim[j] = -C[j];
    X[j] = 1.0f / 256.0f;
    Xs[j] = 0.0f;
  }
  for (int it = 0; it < 20; ++it) {
#pragma unroll
    for (int j = 0; j < 4; ++j) X[j] = X[j] - 0.1f * C[j];
    for (int k = 0; k < 5; ++k) {
#pragma unroll
      for (int j = 0; j < 4; ++j) X[j] = fminf(fmaxf(X[j], 0.0f), 1.0f);
      float s = (X[0] + X[1]) + (X[2] + X[3]);
      s = waveSum(s);
#pragma unroll
      for (int j = 0; j < 4; ++j) X[j] = X[j] / (s + EPSF);
    }
#pragma unroll
    for (int j = 0; j < 4; ++j) Xs[j] += X[j];
  }
  float R[4], bx[4];
#pragma unroll
  for (int j = 0; j < 4; ++j) {
    R[j] = Xs[j] / 20.0f;
    bx[j] = (R[j] > 0.01f) ? R[j] : 0.0f;
  }
  // compact nonzeros of this row into (p, val) lists
  unsigned long long lt = (1ull << lane) - 1ull;
  int base = 0;
#pragma unroll
  for (int j = 0; j < 4; ++j) {
    unsigned long long m = __ballot(bx[j] != 0.0f);
    if (bx[j] != 0.0f) {
      int pos = base + (int)__popcll(m & lt);
      nzidx[o * NP + pos] = lane * 4 + j;
      nzval[o * NP + pos] = bx[j];
    }
    base += (int)__popcll(m);
  }
  if (lane == 0) nzcnt[o] = base;
  // scores
  float mv = -1e30f;
#pragma unroll
  for (int j = 0; j < 4; ++j)
    mv = fmaxf(mv, fminf(fmaxf(R[j], 0.0f), 1.0f) * sim[j]);
  mv = waveMax(mv);
  float4 sc4 = *(const float4*)(score + lane * 4);
  float dv = ((sc4.x * bx[0]) + (sc4.y * bx[1])) + ((sc4.z * bx[2]) + (sc4.w * bx[3]));
  dv = waveSum(dv);
  if (lane == 0) { out[OUTM + o] = mv; out[OUTM + NO + o] = dv; }
}

// --- full_outmask[o][hw] = sum over active p of val * pm[p][hw], float4 per thread ---
__global__ __launch_bounds__(256) void outmask_kernel(const float* __restrict__ pm,
                                                      const int* __restrict__ nzidx,
                                                      const float* __restrict__ nzval,
                                                      const int* __restrict__ nzcnt,
                                                      float* __restrict__ out) {
  int o = blockIdx.y;
  int t = blockIdx.x * 256 + threadIdx.x;   // float4 index
  int hw4 = t * 4;
  if (hw4 >= HW) return;
  int cnt = nzcnt[o];
  float4 acc = make_float4(0.0f, 0.0f, 0.0f, 0.0f);
  for (int i = 0; i < cnt; ++i) {
    int p = nzidx[o * NP + i];
    float v = nzval[o * NP + i];
    float4 m = *(const float4*)(pm + (size_t)p * HW + hw4);
    acc.x = fmaf(v, m.x, acc.x);
    acc.y = fmaf(v, m.y, acc.y);
    acc.z = fmaf(v, m.z, acc.z);
    acc.w = fmaf(v, m.w, acc.w);
  }
  *(float4*)(out + (size_t)o * HW + hw4) = acc;
}

extern "C" void kernel_launch(void* const* d_in, const int* in_sizes, int n_in,
                              void* d_out, int out_size, void* d_ws, size_t ws_size,
                              hipStream_t stream) {
  const float* pf = (const float*)d_in[0];   // proposed_feature [256][256]
  const float* pm = (const float*)d_in[1];   // proposed_mask    [256][240][432]
  const float* tf = (const float*)d_in[2];   // template_feature [2][24][256]
  const float* ml = (const float*)d_in[3];   // mask_last_occ.   [24][240][432]
  const float* sc = (const float*)d_in[4];   // proposal_score   [256]
  float* out = (float*)d_out;
  char* ws = (char*)d_ws;

  // ws layout (bytes):
  u64*   bbits = (u64*)(ws);                      // 256*1620*8 = 3,317,760
  u64*   abits = (u64*)(ws + 3317760);            // 24*1620*8  =   311,040
  // nz lists overlay the abits region (dead after interfeat_kernel):
  int*   nzidx = (int*)(ws + 3317760);            // 24*256*4 = 24,576
  float* nzval = (float*)(ws + 3317760 + 24576);  // 24,576
  int*   nzcnt = (int*)(ws + 3317760 + 49152);    // 96
  float* Cm    = (float*)(ws + 3631136);          // 24*256*4 = 24,576
  float* psum  = (float*)(ws + 3680288);          // 280*16*4 = 17,920

  hipLaunchKernelGGL(pack_kernel,      dim3(16, 280), dim3(256), 0, stream, pm, ml, bbits, abits, psum);
  hipLaunchKernelGGL(interfeat_kernel, dim3(1536),    dim3(256), 0, stream, abits, bbits, pf, tf, psum, Cm);
  hipLaunchKernelGGL(solve_kernel,     dim3(24),      dim3(64),  0, stream, Cm, sc,
                     nzidx, nzval, nzcnt, out);
  hipLaunchKernelGGL(outmask_kernel,   dim3(102, 24), dim3(256), 0, stream, pm, nzidx, nzval, nzcnt, out);
}

// Round 5
// 57.257 us; speedup vs baseline: 3.0992x; 1.2367x over previous
//
#include <hip/hip_runtime.h>

#define HW 103680           // 240*432
#define WORDS 1620          // HW/64 (= 405 groups * 4 ballot-words)
#define NGRP 405            // 256-pixel groups per row
#define NP 256
#define NO 24
#define ND 256
#define EPSF 1e-8f
#define OUTM (NO*HW)        // 2488320

typedef unsigned long long u64;

// DPP wave-64 sum: row_shr 1/2/4/8 + row_bcast:15/31, total lands in lane 63,
// broadcast via readlane. Bitwise-identical tree to the xor butterfly.
__device__ __forceinline__ float waveRedSum(float v) {
  v += __int_as_float(__builtin_amdgcn_update_dpp(0, __float_as_int(v), 0x111, 0xf, 0xf, false));
  v += __int_as_float(__builtin_amdgcn_update_dpp(0, __float_as_int(v), 0x112, 0xf, 0xf, false));
  v += __int_as_float(__builtin_amdgcn_update_dpp(0, __float_as_int(v), 0x114, 0xf, 0xf, false));
  v += __int_as_float(__builtin_amdgcn_update_dpp(0, __float_as_int(v), 0x118, 0xf, 0xf, false));
  v += __int_as_float(__builtin_amdgcn_update_dpp(0, __float_as_int(v), 0x142, 0xf, 0xf, false));
  v += __int_as_float(__builtin_amdgcn_update_dpp(0, __float_as_int(v), 0x143, 0xf, 0xf, false));
  return __int_as_float(__builtin_amdgcn_readlane(__float_as_int(v), 63));
}
__device__ __forceinline__ float waveMax(float v) {
#pragma unroll
  for (int m = 1; m < 64; m <<= 1) v = fmaxf(v, __shfl_xor(v, m, 64));
  return v;
}

// --- bit-pack BOTH mask matrices with float4 loads + 4 ballots per load. ---
__global__ __launch_bounds__(256) void pack_kernel(const float* __restrict__ pm,
                                                   const float* __restrict__ ml,
                                                   u64* __restrict__ bbits,
                                                   u64* __restrict__ abits,
                                                   float* __restrict__ psum) {
  int row = blockIdx.y;
  int tid = threadIdx.x, lane = tid & 63, w = tid >> 6;
  const float* rp;
  u64* bits;
  if (row < NP) { rp = pm + (size_t)row * HW;        bits = bbits + (size_t)row * WORDS; }
  else          { rp = ml + (size_t)(row - NP) * HW; bits = abits + (size_t)(row - NP) * WORDS; }
  int gid = blockIdx.x * 4 + w;        // 0..63
  const float* base = rp + (size_t)(gid * 6) * 256 + lane * 4;
  float4 v[6];
#pragma unroll
  for (int k = 0; k < 6; ++k) v[k] = *(const float4*)(base + k * 256);
  int cnt = 0;
#pragma unroll
  for (int k = 0; k < 6; ++k) {
    int g = gid * 6 + k;
    u64 m0 = __ballot(v[k].x != 0.0f);
    u64 m1 = __ballot(v[k].y != 0.0f);
    u64 m2 = __ballot(v[k].z != 0.0f);
    u64 m3 = __ballot(v[k].w != 0.0f);
    cnt += __popcll(m0) + __popcll(m1) + __popcll(m2) + __popcll(m3);
    if (lane == 0) {
      ulonglong2 s0; s0.x = m0; s0.y = m1;
      ulonglong2 s1; s1.x = m2; s1.y = m3;
      *(ulonglong2*)(bits + g * 4)     = s0;
      *(ulonglong2*)(bits + g * 4 + 2) = s1;
    }
  }
  if (gid < NGRP - 384) {              // remainder groups 384..404
    int g = 384 + gid;
    float4 vv = *(const float4*)(rp + (size_t)g * 256 + lane * 4);
    u64 m0 = __ballot(vv.x != 0.0f);
    u64 m1 = __ballot(vv.y != 0.0f);
    u64 m2 = __ballot(vv.z != 0.0f);
    u64 m3 = __ballot(vv.w != 0.0f);
    cnt += __popcll(m0) + __popcll(m1) + __popcll(m2) + __popcll(m3);
    if (lane == 0) {
      ulonglong2 s0; s0.x = m0; s0.y = m1;
      ulonglong2 s1; s1.x = m2; s1.y = m3;
      *(ulonglong2*)(bits + g * 4)     = s0;
      *(ulonglong2*)(bits + g * 4 + 2) = s1;
    }
  }
  __shared__ int red[4];
  if (lane == 0) red[w] = cnt;
  __syncthreads();
  if (tid == 0) psum[row * 16 + blockIdx.x] =
      (float)((red[0] + red[1]) + (red[2] + red[3]));
}

// --- fused cost matrix: C[o][p] = -(0.5*feature_sim + 0.5*iou). One wave/(o,p). ---
__global__ __launch_bounds__(256) void interfeat_kernel(const u64* __restrict__ ab,
                                                        const u64* __restrict__ bb,
                                                        const float* __restrict__ pf,
                                                        const float* __restrict__ tf,
                                                        const float* __restrict__ psum,
                                                        float* __restrict__ C) {
  int wid = (blockIdx.x * 256 + threadIdx.x) >> 6;   // 0..6143
  int lane = threadIdx.x & 63;
  int o = wid >> 8, p = wid & 255;
  // popcount intersection
  const u64* ar = ab + (size_t)o * WORDS;
  const u64* br = bb + (size_t)p * WORDS;
  int cnt = 0;
  for (int w = lane; w < WORDS; w += 64)
    cnt += (int)__popcll(ar[w] & br[w]);
  float inter = waveRedSum((float)cnt);
  // feature cosine (norms fused)
  float4 f = *(const float4*)(pf + p * ND + lane * 4);
  float4 a = *(const float4*)(tf + o * ND + lane * 4);          // t=0
  float4 b = *(const float4*)(tf + (NO + o) * ND + lane * 4);   // t=1
  float nf = waveRedSum(f.x*f.x + f.y*f.y + f.z*f.z + f.w*f.w);
  float na = waveRedSum(a.x*a.x + a.y*a.y + a.z*a.z + a.w*a.w);
  float nb = waveRedSum(b.x*b.x + b.y*b.y + b.z*b.z + b.w*b.w);
  float d0 = waveRedSum(a.x*f.x + a.y*f.y + a.z*f.z + a.w*f.w);
  float d1 = waveRedSum(b.x*f.x + b.y*f.y + b.z*f.z + b.w*f.w);
  if (lane == 0) {
    float bs = 0.0f, as = 0.0f;
    const float* pb = psum + p * 16;
    const float* pa = psum + (NP + o) * 16;
#pragma unroll
    for (int q = 0; q < 16; ++q) { bs += pb[q]; as += pa[q]; }
    float invf = 1.0f / (sqrtf(nf) + EPSF);
    float inva = 1.0f / (sqrtf(na) + EPSF);
    float invb = 1.0f / (sqrtf(nb) + EPSF);
    float fs  = (d0 * inva + d1 * invb) * invf * 0.5f;   // /T (T=2)
    float uni = as + bs - inter;
    float iou = inter / (uni + EPSF);
    C[wid] = -(fs * 0.5f + iou * 0.5f);
  }
}

// --- 20x5 relaxation + scores + nonzero compaction. 1 wave per row o. ---
__global__ __launch_bounds__(64) void solve_kernel(const float* __restrict__ Cm,
                                                   const float* __restrict__ score,
                                                   int* __restrict__ nzidx,
                                                   float* __restrict__ nzval,
                                                   int* __restrict__ nzcnt,
                                                   float* __restrict__ out) {
  int o = blockIdx.x, lane = threadIdx.x;
  float4 c4 = *(const float4*)(Cm + o * NP + lane * 4);
  float C[4] = {c4.x, c4.y, c4.z, c4.w};
  float sim[4], X[4], Xs[4];
#pragma unroll
  for (int j = 0; j < 4; ++j) {
    sim[j] = -C[j];
    X[j] = 1.0f / 256.0f;
    Xs[j] = 0.0f;
  }
  for (int it = 0; it < 20; ++it) {
#pragma unroll
    for (int j = 0; j < 4; ++j) X[j] = X[j] - 0.1f * C[j];
    for (int k = 0; k < 5; ++k) {
#pragma unroll
      for (int j = 0; j < 4; ++j) X[j] = fminf(fmaxf(X[j], 0.0f), 1.0f);
      float s = waveRedSum((X[0] + X[1]) + (X[2] + X[3]));
#pragma unroll
      for (int j = 0; j < 4; ++j) X[j] = X[j] / (s + EPSF);
    }
#pragma unroll
    for (int j = 0; j < 4; ++j) Xs[j] += X[j];
  }
  float R[4], bx[4];
#pragma unroll
  for (int j = 0; j < 4; ++j) {
    R[j] = Xs[j] / 20.0f;
    bx[j] = (R[j] > 0.01f) ? R[j] : 0.0f;
  }
  // compact nonzeros of this row into (p, val) lists
  unsigned long long lt = (1ull << lane) - 1ull;
  int base = 0;
#pragma unroll
  for (int j = 0; j < 4; ++j) {
    unsigned long long m = __ballot(bx[j] != 0.0f);
    if (bx[j] != 0.0f) {
      int pos = base + (int)__popcll(m & lt);
      nzidx[o * NP + pos] = lane * 4 + j;
      nzval[o * NP + pos] = bx[j];
    }
    base += (int)__popcll(m);
  }
  if (lane == 0) nzcnt[o] = base;
  // scores
  float mv = -1e30f;
#pragma unroll
  for (int j = 0; j < 4; ++j)
    mv = fmaxf(mv, fminf(fmaxf(R[j], 0.0f), 1.0f) * sim[j]);
  mv = waveMax(mv);
  float4 sc4 = *(const float4*)(score + lane * 4);
  float dv = waveRedSum(((sc4.x * bx[0]) + (sc4.y * bx[1])) + ((sc4.z * bx[2]) + (sc4.w * bx[3])));
  if (lane == 0) { out[OUTM + o] = mv; out[OUTM + NO + o] = dv; }
}

// --- full_outmask[o][hw] = sum over active p of val * pm[p][hw], float4 per thread ---
__global__ __launch_bounds__(256) void outmask_kernel(const float* __restrict__ pm,
                                                      const int* __restrict__ nzidx,
                                                      const float* __restrict__ nzval,
                                                      const int* __restrict__ nzcnt,
                                                      float* __restrict__ out) {
  int o = blockIdx.y;
  int t = blockIdx.x * 256 + threadIdx.x;   // float4 index
  int hw4 = t * 4;
  if (hw4 >= HW) return;
  int cnt = nzcnt[o];
  float4 acc = make_float4(0.0f, 0.0f, 0.0f, 0.0f);
  for (int i = 0; i < cnt; ++i) {
    int p = nzidx[o * NP + i];
    float v = nzval[o * NP + i];
    float4 m = *(const float4*)(pm + (size_t)p * HW + hw4);
    acc.x = fmaf(v, m.x, acc.x);
    acc.y = fmaf(v, m.y, acc.y);
    acc.z = fmaf(v, m.z, acc.z);
    acc.w = fmaf(v, m.w, acc.w);
  }
  *(float4*)(out + (size_t)o * HW + hw4) = acc;
}

extern "C" void kernel_launch(void* const* d_in, const int* in_sizes, int n_in,
                              void* d_out, int out_size, void* d_ws, size_t ws_size,
                              hipStream_t stream) {
  const float* pf = (const float*)d_in[0];   // proposed_feature [256][256]
  const float* pm = (const float*)d_in[1];   // proposed_mask    [256][240][432]
  const float* tf = (const float*)d_in[2];   // template_feature [2][24][256]
  const float* ml = (const float*)d_in[3];   // mask_last_occ.   [24][240][432]
  const float* sc = (const float*)d_in[4];   // proposal_score   [256]
  float* out = (float*)d_out;
  char* ws = (char*)d_ws;

  // ws layout (bytes):
  u64*   bbits = (u64*)(ws);                      // 256*1620*8 = 3,317,760
  u64*   abits = (u64*)(ws + 3317760);            // 24*1620*8  =   311,040
  // nz lists overlay the abits region (dead after interfeat_kernel):
  int*   nzidx = (int*)(ws + 3317760);            // 24*256*4 = 24,576
  float* nzval = (float*)(ws + 3317760 + 24576);  // 24,576
  int*   nzcnt = (int*)(ws + 3317760 + 49152);    // 96
  float* Cm    = (float*)(ws + 3631136);          // 24*256*4 = 24,576
  float* psum  = (float*)(ws + 3680288);          // 280*16*4 = 17,920

  hipLaunchKernelGGL(pack_kernel,      dim3(16, 280), dim3(256), 0, stream, pm, ml, bbits, abits, psum);
  hipLaunchKernelGGL(interfeat_kernel, dim3(1536),    dim3(256), 0, stream, abits, bbits, pf, tf, psum, Cm);
  hipLaunchKernelGGL(solve_kernel,     dim3(24),      dim3(64),  0, stream, Cm, sc,
                     nzidx, nzval, nzcnt, out);
  hipLaunchKernelGGL(outmask_kernel,   dim3(102, 24), dim3(256), 0, stream, pm, nzidx, nzval, nzcnt, out);
}

// Round 6
// 57.189 us; speedup vs baseline: 3.1029x; 1.0012x over previous
//
#include <hip/hip_runtime.h>

#define HW 103680           // 240*432
#define WORDS 1620          // HW/64 (= 405 groups * 4 ballot-words)
#define NGRP 405            // 256-pixel groups per row
#define NP 256
#define NO 24
#define ND 256
#define EPSF 1e-8f
#define OUTM (NO*HW)        // 2488320

typedef unsigned long long u64;

// DPP wave-64 sum: row_shr 1/2/4/8 + row_bcast:15/31, result read from lane 63.
// Bitwise-identical tree to the xor butterfly (verified absmax 0.0).
__device__ __forceinline__ float waveRedSum(float v) {
  v += __int_as_float(__builtin_amdgcn_update_dpp(0, __float_as_int(v), 0x111, 0xf, 0xf, false));
  v += __int_as_float(__builtin_amdgcn_update_dpp(0, __float_as_int(v), 0x112, 0xf, 0xf, false));
  v += __int_as_float(__builtin_amdgcn_update_dpp(0, __float_as_int(v), 0x114, 0xf, 0xf, false));
  v += __int_as_float(__builtin_amdgcn_update_dpp(0, __float_as_int(v), 0x118, 0xf, 0xf, false));
  v += __int_as_float(__builtin_amdgcn_update_dpp(0, __float_as_int(v), 0x142, 0xf, 0xf, false));
  v += __int_as_float(__builtin_amdgcn_update_dpp(0, __float_as_int(v), 0x143, 0xf, 0xf, false));
  return __int_as_float(__builtin_amdgcn_readlane(__float_as_int(v), 63));
}
// Same tree for max; old = self so bound-ctrl-invalid lanes fold fmax(v,v)=v.
__device__ __forceinline__ float waveRedMax(float v) {
  int vi = __float_as_int(v);
  v = fmaxf(v, __int_as_float(__builtin_amdgcn_update_dpp(vi, vi, 0x111, 0xf, 0xf, false))); vi = __float_as_int(v);
  v = fmaxf(v, __int_as_float(__builtin_amdgcn_update_dpp(vi, vi, 0x112, 0xf, 0xf, false))); vi = __float_as_int(v);
  v = fmaxf(v, __int_as_float(__builtin_amdgcn_update_dpp(vi, vi, 0x114, 0xf, 0xf, false))); vi = __float_as_int(v);
  v = fmaxf(v, __int_as_float(__builtin_amdgcn_update_dpp(vi, vi, 0x118, 0xf, 0xf, false))); vi = __float_as_int(v);
  v = fmaxf(v, __int_as_float(__builtin_amdgcn_update_dpp(vi, vi, 0x142, 0xf, 0xf, false))); vi = __float_as_int(v);
  v = fmaxf(v, __int_as_float(__builtin_amdgcn_update_dpp(vi, vi, 0x143, 0xf, 0xf, false)));
  return __int_as_float(__builtin_amdgcn_readlane(__float_as_int(v), 63));
}

// --- pure streaming bit-pack: load float4 -> 4 ballots -> 32B store. ---
// grid (7, 280): row = blockIdx.y; 28 waves/row stride over 405 groups.
// No LDS, no syncthreads, no counts (row sums come from popc(a|b) downstream).
__global__ __launch_bounds__(256) void pack_kernel(const float* __restrict__ pm,
                                                   const float* __restrict__ ml,
                                                   u64* __restrict__ bbits,
                                                   u64* __restrict__ abits) {
  int row = blockIdx.y;
  int wir = (blockIdx.x * 256 + threadIdx.x) >> 6;   // wave-in-row, 0..27
  int lane = threadIdx.x & 63;
  const float* rp;
  u64* bits;
  if (row < NP) { rp = pm + (size_t)row * HW;        bits = bbits + (size_t)row * WORDS; }
  else          { rp = ml + (size_t)(row - NP) * HW; bits = abits + (size_t)(row - NP) * WORDS; }
  for (int g = wir; g < NGRP; g += 28) {
    float4 v = *(const float4*)(rp + g * 256 + lane * 4);
    u64 m0 = __ballot(v.x != 0.0f);
    u64 m1 = __ballot(v.y != 0.0f);
    u64 m2 = __ballot(v.z != 0.0f);
    u64 m3 = __ballot(v.w != 0.0f);
    if (lane == 0) {
      ulonglong2 s0; s0.x = m0; s0.y = m1;
      ulonglong2 s1; s1.x = m2; s1.y = m3;
      *(ulonglong2*)(bits + g * 4)     = s0;
      *(ulonglong2*)(bits + g * 4 + 2) = s1;
    }
  }
}

// --- fused cost matrix: C[o][p] = -(0.5*feature_sim + 0.5*iou). One wave/(o,p).
//     union computed directly as popc(a|b) (== asum+bsum-inter, exact ints). ---
__global__ __launch_bounds__(256) void interfeat_kernel(const u64* __restrict__ ab,
                                                        const u64* __restrict__ bb,
                                                        const float* __restrict__ pf,
                                                        const float* __restrict__ tf,
                                                        float* __restrict__ C) {
  int wid = (blockIdx.x * 256 + threadIdx.x) >> 6;   // 0..6143
  int lane = threadIdx.x & 63;
  int o = wid >> 8, p = wid & 255;
  const u64* ar = ab + (size_t)o * WORDS;
  const u64* br = bb + (size_t)p * WORDS;
  int cnt = 0, ucnt = 0;
  for (int w = lane; w < WORDS; w += 64) {
    u64 a = ar[w], b = br[w];
    cnt  += (int)__popcll(a & b);
    ucnt += (int)__popcll(a | b);
  }
  float inter = waveRedSum((float)cnt);
  float uni   = waveRedSum((float)ucnt);
  // feature cosine (norms fused)
  float4 f = *(const float4*)(pf + p * ND + lane * 4);
  float4 a = *(const float4*)(tf + o * ND + lane * 4);          // t=0
  float4 b = *(const float4*)(tf + (NO + o) * ND + lane * 4);   // t=1
  float nf = waveRedSum(f.x*f.x + f.y*f.y + f.z*f.z + f.w*f.w);
  float na = waveRedSum(a.x*a.x + a.y*a.y + a.z*a.z + a.w*a.w);
  float nb = waveRedSum(b.x*b.x + b.y*b.y + b.z*b.z + b.w*b.w);
  float d0 = waveRedSum(a.x*f.x + a.y*f.y + a.z*f.z + a.w*f.w);
  float d1 = waveRedSum(b.x*f.x + b.y*f.y + b.z*f.z + b.w*f.w);
  if (lane == 0) {
    float invf = 1.0f / (sqrtf(nf) + EPSF);
    float inva = 1.0f / (sqrtf(na) + EPSF);
    float invb = 1.0f / (sqrtf(nb) + EPSF);
    float fs  = (d0 * inva + d1 * invb) * invf * 0.5f;   // /T (T=2)
    float iou = inter / (uni + EPSF);
    C[wid] = -(fs * 0.5f + iou * 0.5f);
  }
}

// --- 20x5 relaxation + scores + nonzero compaction. 1 wave per row o. ---
__global__ __launch_bounds__(64) void solve_kernel(const float* __restrict__ Cm,
                                                   const float* __restrict__ score,
                                                   int* __restrict__ nzidx,
                                                   float* __restrict__ nzval,
                                                   int* __restrict__ nzcnt,
                                                   float* __restrict__ out) {
  int o = blockIdx.x, lane = threadIdx.x;
  float4 c4 = *(const float4*)(Cm + o * NP + lane * 4);
  float C[4] = {c4.x, c4.y, c4.z, c4.w};
  float sim[4], X[4], Xs[4];
#pragma unroll
  for (int j = 0; j < 4; ++j) {
    sim[j] = -C[j];
    X[j] = 1.0f / 256.0f;
    Xs[j] = 0.0f;
  }
  for (int it = 0; it < 20; ++it) {
#pragma unroll
    for (int j = 0; j < 4; ++j) X[j] = X[j] - 0.1f * C[j];
    for (int k = 0; k < 5; ++k) {
#pragma unroll
      for (int j = 0; j < 4; ++j) X[j] = fminf(fmaxf(X[j], 0.0f), 1.0f);
      float s = waveRedSum((X[0] + X[1]) + (X[2] + X[3]));
#pragma unroll
      for (int j = 0; j < 4; ++j) X[j] = X[j] / (s + EPSF);
    }
#pragma unroll
    for (int j = 0; j < 4; ++j) Xs[j] += X[j];
  }
  float R[4], bx[4];
#pragma unroll
  for (int j = 0; j < 4; ++j) {
    R[j] = Xs[j] / 20.0f;
    bx[j] = (R[j] > 0.01f) ? R[j] : 0.0f;
  }
  // compact nonzeros of this row into (p, val) lists
  unsigned long long lt = (1ull << lane) - 1ull;
  int base = 0;
#pragma unroll
  for (int j = 0; j < 4; ++j) {
    unsigned long long m = __ballot(bx[j] != 0.0f);
    if (bx[j] != 0.0f) {
      int pos = base + (int)__popcll(m & lt);
      nzidx[o * NP + pos] = lane * 4 + j;
      nzval[o * NP + pos] = bx[j];
    }
    base += (int)__popcll(m);
  }
  if (lane == 0) nzcnt[o] = base;
  // scores
  float mv = -1e30f;
#pragma unroll
  for (int j = 0; j < 4; ++j)
    mv = fmaxf(mv, fminf(fmaxf(R[j], 0.0f), 1.0f) * sim[j]);
  mv = waveRedMax(mv);
  float4 sc4 = *(const float4*)(score + lane * 4);
  float dv = waveRedSum(((sc4.x * bx[0]) + (sc4.y * bx[1])) + ((sc4.z * bx[2]) + (sc4.w * bx[3])));
  if (lane == 0) { out[OUTM + o] = mv; out[OUTM + NO + o] = dv; }
}

// --- full_outmask[o][hw] = sum over active p of val * pm[p][hw], float4 per thread ---
__global__ __launch_bounds__(256) void outmask_kernel(const float* __restrict__ pm,
                                                      const int* __restrict__ nzidx,
                                                      const float* __restrict__ nzval,
                                                      const int* __restrict__ nzcnt,
                                                      float* __restrict__ out) {
  int o = blockIdx.y;
  int t = blockIdx.x * 256 + threadIdx.x;   // float4 index
  int hw4 = t * 4;
  if (hw4 >= HW) return;
  int cnt = nzcnt[o];
  float4 acc = make_float4(0.0f, 0.0f, 0.0f, 0.0f);
  for (int i = 0; i < cnt; ++i) {
    int p = nzidx[o * NP + i];
    float v = nzval[o * NP + i];
    float4 m = *(const float4*)(pm + (size_t)p * HW + hw4);
    acc.x = fmaf(v, m.x, acc.x);
    acc.y = fmaf(v, m.y, acc.y);
    acc.z = fmaf(v, m.z, acc.z);
    acc.w = fmaf(v, m.w, acc.w);
  }
  *(float4*)(out + (size_t)o * HW + hw4) = acc;
}

extern "C" void kernel_launch(void* const* d_in, const int* in_sizes, int n_in,
                              void* d_out, int out_size, void* d_ws, size_t ws_size,
                              hipStream_t stream) {
  const float* pf = (const float*)d_in[0];   // proposed_feature [256][256]
  const float* pm = (const float*)d_in[1];   // proposed_mask    [256][240][432]
  const float* tf = (const float*)d_in[2];   // template_feature [2][24][256]
  const float* ml = (const float*)d_in[3];   // mask_last_occ.   [24][240][432]
  const float* sc = (const float*)d_in[4];   // proposal_score   [256]
  float* out = (float*)d_out;
  char* ws = (char*)d_ws;

  // ws layout (bytes):
  u64*   bbits = (u64*)(ws);                      // 256*1620*8 = 3,317,760
  u64*   abits = (u64*)(ws + 3317760);            // 24*1620*8  =   311,040
  // nz lists overlay the abits region (dead after interfeat_kernel):
  int*   nzidx = (int*)(ws + 3317760);            // 24*256*4 = 24,576
  float* nzval = (float*)(ws + 3317760 + 24576);  // 24,576
  int*   nzcnt = (int*)(ws + 3317760 + 49152);    // 96
  float* Cm    = (float*)(ws + 3631136);          // 24*256*4 = 24,576

  hipLaunchKernelGGL(pack_kernel,      dim3(7, 280), dim3(256), 0, stream, pm, ml, bbits, abits);
  hipLaunchKernelGGL(interfeat_kernel, dim3(1536),   dim3(256), 0, stream, abits, bbits, pf, tf, Cm);
  hipLaunchKernelGGL(solve_kernel,     dim3(24),     dim3(64),  0, stream, Cm, sc,
                     nzidx, nzval, nzcnt, out);
  hipLaunchKernelGGL(outmask_kernel,   dim3(102, 24), dim3(256), 0, stream, pm, nzidx, nzval, nzcnt, out);
}

// Round 7
// 55.972 us; speedup vs baseline: 3.1704x; 1.0217x over previous
//
#include <hip/hip_runtime.h>

#define HW 103680           // 240*432
#define WORDS 1620          // HW/64 (= 405 groups * 4 ballot-words)
#define NGRP 405            // 256-pixel groups per row
#define NP 256
#define NO 24
#define ND 256
#define EPSF 1e-8f
#define OUTM (NO*HW)        // 2488320

typedef unsigned long long u64;

// DPP wave-64 sum: row_shr 1/2/4/8 + row_bcast:15/31, result read from lane 63.
// Bitwise-identical tree to the xor butterfly (verified absmax 0.0).
__device__ __forceinline__ float waveRedSum(float v) {
  v += __int_as_float(__builtin_amdgcn_update_dpp(0, __float_as_int(v), 0x111, 0xf, 0xf, false));
  v += __int_as_float(__builtin_amdgcn_update_dpp(0, __float_as_int(v), 0x112, 0xf, 0xf, false));
  v += __int_as_float(__builtin_amdgcn_update_dpp(0, __float_as_int(v), 0x114, 0xf, 0xf, false));
  v += __int_as_float(__builtin_amdgcn_update_dpp(0, __float_as_int(v), 0x118, 0xf, 0xf, false));
  v += __int_as_float(__builtin_amdgcn_update_dpp(0, __float_as_int(v), 0x142, 0xf, 0xf, false));
  v += __int_as_float(__builtin_amdgcn_update_dpp(0, __float_as_int(v), 0x143, 0xf, 0xf, false));
  return __int_as_float(__builtin_amdgcn_readlane(__float_as_int(v), 63));
}
// Same tree for max; old = self so bound-ctrl-invalid lanes fold fmax(v,v)=v.
__device__ __forceinline__ float waveRedMax(float v) {
  int vi = __float_as_int(v);
  v = fmaxf(v, __int_as_float(__builtin_amdgcn_update_dpp(vi, vi, 0x111, 0xf, 0xf, false))); vi = __float_as_int(v);
  v = fmaxf(v, __int_as_float(__builtin_amdgcn_update_dpp(vi, vi, 0x112, 0xf, 0xf, false))); vi = __float_as_int(v);
  v = fmaxf(v, __int_as_float(__builtin_amdgcn_update_dpp(vi, vi, 0x114, 0xf, 0xf, false))); vi = __float_as_int(v);
  v = fmaxf(v, __int_as_float(__builtin_amdgcn_update_dpp(vi, vi, 0x118, 0xf, 0xf, false))); vi = __float_as_int(v);
  v = fmaxf(v, __int_as_float(__builtin_amdgcn_update_dpp(vi, vi, 0x142, 0xf, 0xf, false))); vi = __float_as_int(v);
  v = fmaxf(v, __int_as_float(__builtin_amdgcn_update_dpp(vi, vi, 0x143, 0xf, 0xf, false)));
  return __int_as_float(__builtin_amdgcn_readlane(__float_as_int(v), 63));
}

// --- pure streaming bit-pack, 2x unrolled for load ILP. ---
__device__ __forceinline__ void pack_group(const float* __restrict__ rp,
                                           u64* __restrict__ bits,
                                           int g, int lane, float4 v) {
  u64 m0 = __ballot(v.x != 0.0f);
  u64 m1 = __ballot(v.y != 0.0f);
  u64 m2 = __ballot(v.z != 0.0f);
  u64 m3 = __ballot(v.w != 0.0f);
  if (lane == 0) {
    ulonglong2 s0; s0.x = m0; s0.y = m1;
    ulonglong2 s1; s1.x = m2; s1.y = m3;
    *(ulonglong2*)(bits + g * 4)     = s0;
    *(ulonglong2*)(bits + g * 4 + 2) = s1;
  }
}

__global__ __launch_bounds__(256) void pack_kernel(const float* __restrict__ pm,
                                                   const float* __restrict__ ml,
                                                   u64* __restrict__ bbits,
                                                   u64* __restrict__ abits) {
  int row = blockIdx.y;
  int wir = (blockIdx.x * 256 + threadIdx.x) >> 6;   // wave-in-row, 0..27
  int lane = threadIdx.x & 63;
  const float* rp;
  u64* bits;
  if (row < NP) { rp = pm + (size_t)row * HW;        bits = bbits + (size_t)row * WORDS; }
  else          { rp = ml + (size_t)(row - NP) * HW; bits = abits + (size_t)(row - NP) * WORDS; }
  int g = wir;
  while (g + 28 < NGRP) {
    float4 v0 = *(const float4*)(rp + g * 256 + lane * 4);
    float4 v1 = *(const float4*)(rp + (g + 28) * 256 + lane * 4);
    pack_group(rp, bits, g, lane, v0);
    pack_group(rp, bits, g + 28, lane, v1);
    g += 56;
  }
  if (g < NGRP) {
    float4 v0 = *(const float4*)(rp + g * 256 + lane * 4);
    pack_group(rp, bits, g, lane, v0);
  }
}

// --- fused cost matrix: C[o][p] = -(0.5*feature_sim + 0.5*iou). One wave/(o,p).
//     union computed directly as popc(a|b). De-ragged loop for ILP. ---
__global__ __launch_bounds__(256) void interfeat_kernel(const u64* __restrict__ ab,
                                                        const u64* __restrict__ bb,
                                                        const float* __restrict__ pf,
                                                        const float* __restrict__ tf,
                                                        float* __restrict__ C) {
  int wid = (blockIdx.x * 256 + threadIdx.x) >> 6;   // 0..6143
  int lane = threadIdx.x & 63;
  int o = wid >> 8, p = wid & 255;
  // issue feature loads first; they complete before the popcount stream's tail
  float4 f = *(const float4*)(pf + p * ND + lane * 4);
  float4 a = *(const float4*)(tf + o * ND + lane * 4);          // t=0
  float4 b = *(const float4*)(tf + (NO + o) * ND + lane * 4);   // t=1
  const u64* arl = ab + (size_t)o * WORDS + lane;
  const u64* brl = bb + (size_t)p * WORDS + lane;
  int cnt = 0, ucnt = 0;
#pragma unroll 5
  for (int k = 0; k < 25; ++k) {                    // uniform 25 iters, all lanes
    u64 av = arl[k * 64], bv = brl[k * 64];
    cnt  += (int)__popcll(av & bv);
    ucnt += (int)__popcll(av | bv);
  }
  if (lane < WORDS - 1600) {                        // tail words 1600..1619
    u64 av = arl[1600], bv = brl[1600];
    cnt  += (int)__popcll(av & bv);
    ucnt += (int)__popcll(av | bv);
  }
  float inter = waveRedSum((float)cnt);
  float uni   = waveRedSum((float)ucnt);
  float nf = waveRedSum(f.x*f.x + f.y*f.y + f.z*f.z + f.w*f.w);
  float na = waveRedSum(a.x*a.x + a.y*a.y + a.z*a.z + a.w*a.w);
  float nb = waveRedSum(b.x*b.x + b.y*b.y + b.z*b.z + b.w*b.w);
  float d0 = waveRedSum(a.x*f.x + a.y*f.y + a.z*f.z + a.w*f.w);
  float d1 = waveRedSum(b.x*f.x + b.y*f.y + b.z*f.z + b.w*f.w);
  if (lane == 0) {
    float invf = 1.0f / (sqrtf(nf) + EPSF);
    float inva = 1.0f / (sqrtf(na) + EPSF);
    float invb = 1.0f / (sqrtf(nb) + EPSF);
    float fs  = (d0 * inva + d1 * invb) * invf * 0.5f;   // /T (T=2)
    float iou = inter / (uni + EPSF);
    C[wid] = -(fs * 0.5f + iou * 0.5f);
  }
}

// --- 20x5 relaxation + scores + nonzero compaction. 1 wave per row o. ---
__global__ __launch_bounds__(64) void solve_kernel(const float* __restrict__ Cm,
                                                   const float* __restrict__ score,
                                                   int* __restrict__ nzidx,
                                                   float* __restrict__ nzval,
                                                   int* __restrict__ nzcnt,
                                                   float* __restrict__ out) {
  int o = blockIdx.x, lane = threadIdx.x;
  float4 c4 = *(const float4*)(Cm + o * NP + lane * 4);
  float C[4] = {c4.x, c4.y, c4.z, c4.w};
  float sim[4], X[4], Xs[4];
#pragma unroll
  for (int j = 0; j < 4; ++j) {
    sim[j] = -C[j];
    X[j] = 1.0f / 256.0f;
    Xs[j] = 0.0f;
  }
  for (int it = 0; it < 20; ++it) {
#pragma unroll
    for (int j = 0; j < 4; ++j) X[j] = X[j] - 0.1f * C[j];
    for (int k = 0; k < 5; ++k) {
#pragma unroll
      for (int j = 0; j < 4; ++j) X[j] = fminf(fmaxf(X[j], 0.0f), 1.0f);
      float s = waveRedSum((X[0] + X[1]) + (X[2] + X[3]));
#pragma unroll
      for (int j = 0; j < 4; ++j) X[j] = X[j] / (s + EPSF);
    }
#pragma unroll
    for (int j = 0; j < 4; ++j) Xs[j] += X[j];
  }
  float R[4], bx[4];
#pragma unroll
  for (int j = 0; j < 4; ++j) {
    R[j] = Xs[j] / 20.0f;
    bx[j] = (R[j] > 0.01f) ? R[j] : 0.0f;
  }
  // compact nonzeros of this row into (p, val) lists (p ascending)
  unsigned long long lt = (1ull << lane) - 1ull;
  int base = 0;
#pragma unroll
  for (int j = 0; j < 4; ++j) {
    unsigned long long m = __ballot(bx[j] != 0.0f);
    if (bx[j] != 0.0f) {
      int pos = base + (int)__popcll(m & lt);
      nzidx[o * NP + pos] = lane * 4 + j;
      nzval[o * NP + pos] = bx[j];
    }
    base += (int)__popcll(m);
  }
  if (lane == 0) nzcnt[o] = base;
  // scores
  float mv = -1e30f;
#pragma unroll
  for (int j = 0; j < 4; ++j)
    mv = fmaxf(mv, fminf(fmaxf(R[j], 0.0f), 1.0f) * sim[j]);
  mv = waveRedMax(mv);
  float4 sc4 = *(const float4*)(score + lane * 4);
  float dv = waveRedSum(((sc4.x * bx[0]) + (sc4.y * bx[1])) + ((sc4.z * bx[2]) + (sc4.w * bx[3])));
  if (lane == 0) { out[OUTM + o] = mv; out[OUTM + NO + o] = dv; }
}

// --- full_outmask from BITS: wave per (o, 256-px group). Word g*4+c bit L
//     <-> px g*256 + 4L + c, so lane's float4 output uses words m0..m3. ---
__global__ __launch_bounds__(256) void outmask_kernel(const u64* __restrict__ bb,
                                                      const int* __restrict__ nzidx,
                                                      const float* __restrict__ nzval,
                                                      const int* __restrict__ nzcnt,
                                                      float* __restrict__ out) {
  int o = blockIdx.y;
  int g = blockIdx.x * 4 + (threadIdx.x >> 6);
  int lane = threadIdx.x & 63;
  if (g >= NGRP) return;
  int cnt = nzcnt[o];
  float ax = 0.0f, ay = 0.0f, az = 0.0f, aw = 0.0f;
  for (int i = 0; i < cnt; ++i) {
    int p   = nzidx[o * NP + i];          // wave-uniform
    float v = nzval[o * NP + i];
    const u64* wp = bb + (size_t)p * WORDS + g * 4;
    u64 m0 = wp[0], m1 = wp[1], m2 = wp[2], m3 = wp[3];
    ax += ((m0 >> lane) & 1ull) ? v : 0.0f;
    ay += ((m1 >> lane) & 1ull) ? v : 0.0f;
    az += ((m2 >> lane) & 1ull) ? v : 0.0f;
    aw += ((m3 >> lane) & 1ull) ? v : 0.0f;
  }
  *(float4*)(out + (size_t)o * HW + g * 256 + lane * 4) = make_float4(ax, ay, az, aw);
}

extern "C" void kernel_launch(void* const* d_in, const int* in_sizes, int n_in,
                              void* d_out, int out_size, void* d_ws, size_t ws_size,
                              hipStream_t stream) {
  const float* pf = (const float*)d_in[0];   // proposed_feature [256][256]
  const float* pm = (const float*)d_in[1];   // proposed_mask    [256][240][432]
  const float* tf = (const float*)d_in[2];   // template_feature [2][24][256]
  const float* ml = (const float*)d_in[3];   // mask_last_occ.   [24][240][432]
  const float* sc = (const float*)d_in[4];   // proposal_score   [256]
  float* out = (float*)d_out;
  char* ws = (char*)d_ws;

  // ws layout (bytes):
  u64*   bbits = (u64*)(ws);                      // 256*1620*8 = 3,317,760
  u64*   abits = (u64*)(ws + 3317760);            // 24*1620*8  =   311,040
  // nz lists overlay the abits region (dead after interfeat_kernel):
  int*   nzidx = (int*)(ws + 3317760);            // 24*256*4 = 24,576
  float* nzval = (float*)(ws + 3317760 + 24576);  // 24,576
  int*   nzcnt = (int*)(ws + 3317760 + 49152);    // 96
  float* Cm    = (float*)(ws + 3631136);          // 24*256*4 = 24,576

  hipLaunchKernelGGL(pack_kernel,      dim3(7, 280),  dim3(256), 0, stream, pm, ml, bbits, abits);
  hipLaunchKernelGGL(interfeat_kernel, dim3(1536),    dim3(256), 0, stream, abits, bbits, pf, tf, Cm);
  hipLaunchKernelGGL(solve_kernel,     dim3(24),      dim3(64),  0, stream, Cm, sc,
                     nzidx, nzval, nzcnt, out);
  hipLaunchKernelGGL(outmask_kernel,   dim3(102, 24), dim3(256), 0, stream, bbits, nzidx, nzval, nzcnt, out);
}